// Round 10
// baseline (482.748 us; speedup 1.0000x reference)
//
#include <hip/hip_runtime.h>

// ShiftWindowMSA (Swin) fused kernels for MI355X (gfx950).
// B=16, H=W=64, C=512, NH=16, hd=32, WS=8, SS=4 -> 1024 windows x 64 tokens.
//
// R10: monolith with LDS cut to 49152 B/block so THREE 4-wave blocks fit per
// CU (3 waves/SIMD) under plain __launch_bounds__(256,2):
//  - actual occupancy = min(LDS cap, VGPR cap); VGPR measured 128 -> 16 waves
//    allowed; only LDS (old xs=65KB) capped us at 2 blocks. (256,3) is never
//    used (R2/R8: forced-budget spill catastrophe, rule hardened).
//  - phase 1 = R7's proven swizzled per-wave scratch (6144 sh/wave, 49152 B).
//  - phase 2 = proj with HALF-K exchange: xsh[64][264] bf16 (33792 B, overlaid)
//    holds half the y channels at a time; 2 rounds x 2 out-ch passes, B-row
//    remap ch = 128*(c'>>6) + 64*rnd + (c'&63) (16B-contiguous since kk is
//    32-aligned). po (packed y) held in regs across rounds (R1-proven layout).
// Evidence ledger: R1/R9 monolith 403-412 (MfmaUtil 15, Occ 23, latency-bound);
// splits pay HBM round-trips (R5 280us k_qkv, R7 508 total); R9 SW-pipelining
// null (compiler already hoists).
// Fallback (ws < 66 MiB): R0 monolithic k_legacy.

typedef short  short8  __attribute__((ext_vector_type(8)));
typedef short  short4v __attribute__((ext_vector_type(4)));
typedef float  floatx4 __attribute__((ext_vector_type(4)));

#define DEVI static __device__ __forceinline__

DEVI unsigned short f2bf(float f) {
    union { float f; unsigned int u; } v;
    v.f = f;
    return (unsigned short)((v.u + 0x7fffu + ((v.u >> 16) & 1u)) >> 16);
}

// ---------------------------------------------------------------------------
// wcvt: qkv_w (1536x512) then proj_w (512x512) fp32 -> bf16 into wbf.
// ---------------------------------------------------------------------------
__global__ void wcvt(const float* __restrict__ qkv_w,
                     const float* __restrict__ proj_w,
                     unsigned short* __restrict__ wbf) {
    const int idx = ((blockIdx.x << 8) + threadIdx.x) << 2;
    const float* src = (idx < 786432) ? (qkv_w + idx) : (proj_w + (idx - 786432));
    const floatx4 v = *(const floatx4*)src;
    short4v o;
    o[0] = (short)f2bf(v[0]); o[1] = (short)f2bf(v[1]);
    o[2] = (short)f2bf(v[2]); o[3] = (short)f2bf(v[3]);
    *(short4v*)(wbf + idx) = o;
}

// ---------------------------------------------------------------------------
// xcvt: gather cyclic-shifted windows of query -> xw bf16 [win][kc][tok][32].
// ---------------------------------------------------------------------------
__global__ void xcvt(const float* __restrict__ query,
                     unsigned short* __restrict__ xw) {
    const int bid = blockIdx.x;
    const int x   = bid & 7;
    const int s   = bid >> 3;                           // 0..2047
    const int win = (x << 7) + (s >> 4);
    const int rem = ((s & 15) << 8) + threadIdx.x;      // 0..4095
    const int jc  = rem & 3;                            // 8-short chunk in 32
    const int tok = (rem >> 2) & 63;
    const int kc  = rem >> 8;                           // 0..15
    const int b   = win >> 6, wy = (win >> 3) & 7, wx = win & 7;
    const int ty  = tok >> 3, tx = tok & 7;
    const int gh  = ((wy << 3) + ty + 4) & 63;
    const int gw  = ((wx << 3) + tx + 4) & 63;
    const float* src = query + (((b << 12) + (gh << 6) + gw) << 9) + (kc << 5) + (jc << 3);
    const floatx4 v0 = *(const floatx4*)src;
    const floatx4 v1 = *(const floatx4*)(src + 4);
    short8 sv;
    sv[0] = (short)f2bf(v0[0]); sv[1] = (short)f2bf(v0[1]);
    sv[2] = (short)f2bf(v0[2]); sv[3] = (short)f2bf(v0[3]);
    sv[4] = (short)f2bf(v1[0]); sv[5] = (short)f2bf(v1[1]);
    sv[6] = (short)f2bf(v1[2]); sv[7] = (short)f2bf(v1[3]);
    *(short8*)(xw + (win << 15) + (kc << 11) + (tok << 5) + (jc << 3)) = sv;
}

// ---------------------------------------------------------------------------
// k_fused3: 1 block = 1 window, 4 waves x 4 heads, LDS 49152 B (3 blocks/CU).
// Phase 1 (R7-proven): per head, single-pass QKV GEMM (96-acc) -> swizzled
// wave-private LDS -> QK^T -> softmax -> PV -> po (packed bf16 y in regs).
// Phase 2: proj with half-K exchange via xsh[64][264] (overlaid on scratch).
// ---------------------------------------------------------------------------
__global__ __launch_bounds__(256, 2)
void k_fused3(const unsigned short* __restrict__ wbf,
              const unsigned short* __restrict__ xw,
              const float* __restrict__ qkv_b,
              const float* __restrict__ proj_b,
              const float* __restrict__ bias_table,
              float* __restrict__ out)
{
    __shared__ __align__(16) unsigned short smem[24576];   // 49152 B

    const int tid  = threadIdx.x;
    const int lane = tid & 63;
    const int l15  = lane & 15;
    const int quad = lane >> 4;
    const int wave = tid >> 6;

    const int win = blockIdx.x;
    const int b   = win >> 6;
    const int wy  = (win >> 3) & 7;
    const int wx  = win & 7;
    const int mid = ((wy == 7) ? 2 : 0) | ((wx == 7) ? 1 : 0);

    unsigned short* wbs = smem + wave * 6144;
    unsigned short* qbf = wbs;                          // [64][32] swizzled
    unsigned short* kbf = wbs + 2048;                   // [64][32] swizzled
    unsigned short* vT  = wbs + 4096;                   // [32][64] swizzled
    unsigned short* pbf = wbs;                          // [64][64] swizzled, overlays q+k

    const int sw4 = (l15 & 3) ^ (l15 >> 2);             // q/k read swizzle
    const int sw8 = (l15 & 7) ^ (l15 >> 3);             // vT/p read swizzle

    const unsigned short* xa = xw + (win << 15) + (l15 << 5) + (quad << 3);
    const float scale = 0.17677669529663687f;           // 1/sqrt(32)
    const floatx4 fz = {0.f, 0.f, 0.f, 0.f};

    unsigned int po[4][16];                             // packed bf16 y per head

    for (int hh = 0; hh < 4; ++hh) {
        const int h = (wave << 2) + hh;

        // ---------------- QKV projection (single pass, 96 acc) --------------
        floatx4 accq[4][2], acck[4][2], accv[4][2];
        #pragma unroll
        for (int mt = 0; mt < 4; ++mt)
            #pragma unroll
            for (int nt = 0; nt < 2; ++nt) { accq[mt][nt] = fz; acck[mt][nt] = fz; accv[mt][nt] = fz; }

        const unsigned short* wq = wbf + ((h << 5) + l15) * 512 + (quad << 3);
        const unsigned short* wk = wq + 262144;
        const unsigned short* wv = wk + 262144;

        #pragma unroll 2
        for (int kk = 0; kk < 512; kk += 32) {
            short8 a[4], bq[2], bk2[2], bv2[2];
            #pragma unroll
            for (int mt = 0; mt < 4; ++mt)
                a[mt] = *(const short8*)(xa + (kk << 6) + (mt << 9));
            #pragma unroll
            for (int nt = 0; nt < 2; ++nt) {
                const int ro = (nt << 4) * 512 + kk;
                bq[nt]  = *(const short8*)(wq + ro);
                bk2[nt] = *(const short8*)(wk + ro);
                bv2[nt] = *(const short8*)(wv + ro);
            }
            #pragma unroll
            for (int nt = 0; nt < 2; ++nt)
                #pragma unroll
                for (int mt = 0; mt < 4; ++mt) {
                    accq[mt][nt] = __builtin_amdgcn_mfma_f32_16x16x32_bf16(a[mt], bq[nt],  accq[mt][nt], 0, 0, 0);
                    acck[mt][nt] = __builtin_amdgcn_mfma_f32_16x16x32_bf16(a[mt], bk2[nt], acck[mt][nt], 0, 0, 0);
                    accv[mt][nt] = __builtin_amdgcn_mfma_f32_16x16x32_bf16(a[mt], bv2[nt], accv[mt][nt], 0, 0, 0);
                }
        }

        // ---- bias + stage q,k (swizzled) and vT (swizzled) into LDS ---------
        #pragma unroll
        for (int nt = 0; nt < 2; ++nt) {
            const int cix = (h << 5) + (nt << 4) + l15;
            const float bq_ = qkv_b[cix];
            const float bk_ = qkv_b[512 + cix];
            const float bv_ = qkv_b[1024 + cix];
            #pragma unroll
            for (int mt = 0; mt < 4; ++mt) {
                short4v vv;
                #pragma unroll
                for (int r = 0; r < 4; ++r) {
                    const int row = (mt << 4) + (quad << 2) + r;
                    const int ph  = (2 * nt + (l15 >> 3)) ^ (row & 3) ^ ((row >> 2) & 3);
                    const int off = (row << 5) + (l15 & 7) + (ph << 3);
                    qbf[off] = f2bf(accq[mt][nt][r] + bq_);
                    kbf[off] = f2bf(acck[mt][nt][r] + bk_);
                    vv[r] = (short)f2bf(accv[mt][nt][r] + bv_);
                }
                const int vph = (2 * mt + (quad >> 1)) ^ sw8;
                *(short4v*)&vT[(((nt << 4) + l15) << 6) + ((quad & 1) << 2) + (vph << 3)] = vv;
            }
        }
        // (no barrier: scratch is wave-private)

        // ---------------- Q K^T ----------------------------------------------
        short8 qa[4], ka[4];
        #pragma unroll
        for (int t = 0; t < 4; ++t) {
            const int off = ((((t << 4) + l15)) << 5) + ((quad ^ sw4) << 3);
            qa[t] = *(const short8*)&qbf[off];
            ka[t] = *(const short8*)&kbf[off];
        }
        floatx4 s4[4][4];
        #pragma unroll
        for (int mt = 0; mt < 4; ++mt)
            #pragma unroll
            for (int nt = 0; nt < 4; ++nt)
                s4[mt][nt] = __builtin_amdgcn_mfma_f32_16x16x32_bf16(qa[mt], ka[nt], fz, 0, 0, 0);

        // ------- logits: scale + rel-pos bias (closed-form idx) + shift mask --
        int  gjv[4]; bool jrow[4], jcol[4];
        #pragma unroll
        for (int nt = 0; nt < 4; ++nt) {
            const int j  = (nt << 4) + l15;
            const int j2 = 63 - j;
            gjv[nt]  = 15 * (j2 >> 3) + (j2 & 7);
            jrow[nt] = (j >> 3) < 4;
            jcol[nt] = (j & 7) < 4;
        }
        #pragma unroll
        for (int mt = 0; mt < 4; ++mt) {
            const int i0  = (mt << 4) + (quad << 2);
            const int fi0 = 15 * (i0 >> 3) + (i0 & 7);
            const bool irow = (i0 >> 3) < 4;
            const bool icol = (i0 & 7) == 0;
            #pragma unroll
            for (int nt = 0; nt < 4; ++nt) {
                float mval = 0.0f;
                if ((mid & 2) && (irow != jrow[nt])) mval = -100.0f;
                if ((mid & 1) && (icol != jcol[nt])) mval = -100.0f;
                const float* bp = bias_table + (fi0 + gjv[nt]) * 16 + h;
                #pragma unroll
                for (int r = 0; r < 4; ++r)
                    s4[mt][nt][r] = s4[mt][nt][r] * scale + bp[r * 16] + mval;
            }
        }

        // ---- softmax (max-subtracted, normalized) -> P in swizzled LDS -------
        #pragma unroll
        for (int mt = 0; mt < 4; ++mt)
            #pragma unroll
            for (int r = 0; r < 4; ++r) {
                float m = fmaxf(fmaxf(s4[mt][0][r], s4[mt][1][r]),
                                fmaxf(s4[mt][2][r], s4[mt][3][r]));
                m = fmaxf(m, __shfl_xor(m, 1));
                m = fmaxf(m, __shfl_xor(m, 2));
                m = fmaxf(m, __shfl_xor(m, 4));
                m = fmaxf(m, __shfl_xor(m, 8));
                float loc = 0.0f;
                #pragma unroll
                for (int nt = 0; nt < 4; ++nt) {
                    s4[mt][nt][r] = __expf(s4[mt][nt][r] - m);
                    loc += s4[mt][nt][r];
                }
                loc += __shfl_xor(loc, 1);
                loc += __shfl_xor(loc, 2);
                loc += __shfl_xor(loc, 4);
                loc += __shfl_xor(loc, 8);
                const float inv = 1.0f / loc;           // loc >= 1 (max entry = 1)
                const int row = (mt << 4) + (quad << 2) + r;
                #pragma unroll
                for (int nt = 0; nt < 4; ++nt) {
                    const int ph = (2 * nt + (l15 >> 3)) ^ (row & 7) ^ ((row >> 3) & 1);
                    pbf[(row << 6) + (l15 & 7) + (ph << 3)] = f2bf(s4[mt][nt][r] * inv);
                }
            }
        // (no barrier: pbf is wave-private)

        // ---------------- P V -> po (packed bf16, R1 layout) ------------------
        short8 pa[4][2], va[2][2];
        #pragma unroll
        for (int mt = 0; mt < 4; ++mt)
            #pragma unroll
            for (int ks = 0; ks < 2; ++ks)
                pa[mt][ks] = *(const short8*)&pbf[((((mt << 4) + l15)) << 6) + ((((ks << 2) + quad) ^ sw8) << 3)];
        #pragma unroll
        for (int nt = 0; nt < 2; ++nt)
            #pragma unroll
            for (int ks = 0; ks < 2; ++ks)
                va[nt][ks] = *(const short8*)&vT[((((nt << 4) + l15)) << 6) + ((((ks << 2) + quad) ^ sw8) << 3)];

        #pragma unroll
        for (int mt = 0; mt < 4; ++mt)
            #pragma unroll
            for (int nt = 0; nt < 2; ++nt) {
                floatx4 acc = fz;
                acc = __builtin_amdgcn_mfma_f32_16x16x32_bf16(pa[mt][0], va[nt][0], acc, 0, 0, 0);
                acc = __builtin_amdgcn_mfma_f32_16x16x32_bf16(pa[mt][1], va[nt][1], acc, 0, 0, 0);
                const int pi = ((mt << 1) + nt) << 1;
                po[hh][pi]     = (unsigned int)f2bf(acc[0]) | ((unsigned int)f2bf(acc[1]) << 16);
                po[hh][pi + 1] = (unsigned int)f2bf(acc[2]) | ((unsigned int)f2bf(acc[3]) << 16);
            }
    }

    // ---------------- phase 2: proj with half-K exchange ----------------------
    // xsh[64][264] bf16 (16896 sh = 33792 B, overlays the per-wave scratch).
    // Round rnd covers real channels { 128*w + 64*rnd + c : w in 0..3, c in 0..63 },
    // i.e. heads {4w+2rnd, 4w+2rnd+1}. c' index in xsh = 64*w + c;
    // real ch(c') = 128*(c'>>6) + 64*rnd + (c'&63).
    unsigned short* xsh = smem;
    const unsigned short* pwb = wbf + 786432;

    for (int pass = 0; pass < 2; ++pass) {
        const int co0 = (wave << 7) + (pass << 6);
        floatx4 acc[4][4];
        #pragma unroll
        for (int mt = 0; mt < 4; ++mt)
            #pragma unroll
            for (int nt = 0; nt < 4; ++nt) acc[mt][nt] = fz;

        const unsigned short* wp = pwb + (co0 + l15) * 512;

        for (int rnd = 0; rnd < 2; ++rnd) {
            __syncthreads();   // previous readers of xsh (or phase-1 scratch) done
            #pragma unroll
            for (int hi = 0; hi < 2; ++hi) {
                const int hh = (rnd << 1) + hi;
                const int c0 = (wave << 6) + (hi << 5) + l15;
                #pragma unroll
                for (int mt = 0; mt < 4; ++mt)
                    #pragma unroll
                    for (int nt = 0; nt < 2; ++nt) {
                        const int pi = ((mt << 1) + nt) << 1;
                        #pragma unroll
                        for (int r = 0; r < 4; ++r) {
                            const int row = (mt << 4) + (quad << 2) + r;
                            const unsigned int w = po[hh][pi + (r >> 1)];
                            xsh[row * 264 + c0 + (nt << 4)] =
                                (unsigned short)((w >> ((r & 1) << 4)) & 0xffffu);
                        }
                    }
            }
            __syncthreads();   // all waves' y-half published

            #pragma unroll 2
            for (int kk = 0; kk < 256; kk += 32) {
                const int rb = ((kk >> 6) << 7) + (rnd << 6) + (kk & 63) + (quad << 3);
                short8 a[4], bfr[4];
                #pragma unroll
                for (int mt = 0; mt < 4; ++mt)
                    a[mt] = *(const short8*)&xsh[((mt << 4) + l15) * 264 + kk + (quad << 3)];
                #pragma unroll
                for (int nt = 0; nt < 4; ++nt)
                    bfr[nt] = *(const short8*)(wp + (nt << 4) * 512 + rb);
                #pragma unroll
                for (int nt = 0; nt < 4; ++nt)
                    #pragma unroll
                    for (int mt = 0; mt < 4; ++mt)
                        acc[mt][nt] = __builtin_amdgcn_mfma_f32_16x16x32_bf16(a[mt], bfr[nt], acc[mt][nt], 0, 0, 0);
            }
        }

        // epilogue: bias + window-reverse + reverse-roll scatter
        #pragma unroll
        for (int nt = 0; nt < 4; ++nt) {
            const float pb_ = proj_b[co0 + (nt << 4) + l15];
            #pragma unroll
            for (int mt = 0; mt < 4; ++mt)
                #pragma unroll
                for (int r = 0; r < 4; ++r) {
                    const int tok = (mt << 4) + (quad << 2) + r;
                    const int ty = tok >> 3, tx = tok & 7;
                    const int gh = ((wy << 3) + ty + 4) & 63;
                    const int gw = ((wx << 3) + tx + 4) & 63;
                    out[(((b << 12) + (gh << 6) + gw) << 9) + co0 + (nt << 4) + l15] =
                        acc[mt][nt][r] + pb_;
                }
        }
    }
}

// ---------------------------------------------------------------------------
// Fallback (ws < 66 MiB): R0 monolithic kernel (stages window in LDS).
// ---------------------------------------------------------------------------
__global__ __launch_bounds__(256, 1)
void k_legacy(const float* __restrict__ query,
              const unsigned short* __restrict__ wbf,
              const float* __restrict__ qkv_b,
              const float* __restrict__ proj_b,
              const float* __restrict__ bias_table,
              float* __restrict__ out)
{
    __shared__ __align__(16) unsigned short smem[62976];

    const int tid  = threadIdx.x;
    const int lane = tid & 63;
    const int l15  = lane & 15;
    const int quad = lane >> 4;
    const int wave = tid >> 6;

    const int win = blockIdx.x;
    const int b   = win >> 6;
    const int wy  = (win >> 3) & 7;
    const int wx  = win & 7;
    const int mid = ((wy == 7) ? 2 : 0) | ((wx == 7) ? 1 : 0);

    unsigned short* xs  = smem;
    unsigned short* wb  = smem + 33280 + wave * 7424;
    unsigned short* qbf = wb;
    unsigned short* kbf = wb + 2560;
    unsigned short* vT  = wb + 5120;
    unsigned short* pbf = wb;

    #pragma unroll
    for (int it = 0; it < 32; ++it) {
        const int c   = tid + (it << 8);
        const int tok = c >> 7;
        const int fo  = (c & 127) << 2;
        const int ty  = tok >> 3, tx = tok & 7;
        const int gh  = ((wy << 3) + ty + 4) & 63;
        const int gw  = ((wx << 3) + tx + 4) & 63;
        const floatx4 v = *(const floatx4*)(query + (((b << 12) + (gh << 6) + gw) << 9) + fo);
        short4v s;
        s[0] = (short)f2bf(v[0]); s[1] = (short)f2bf(v[1]);
        s[2] = (short)f2bf(v[2]); s[3] = (short)f2bf(v[3]);
        *(short4v*)&xs[tok * 520 + fo] = s;
    }
    __syncthreads();

    const float scale = 0.17677669529663687f;
    const floatx4 fz = {0.f, 0.f, 0.f, 0.f};
    unsigned int po[4][16];

    for (int hh = 0; hh < 4; ++hh) {
        const int h = (wave << 2) + hh;
        floatx4 accq[4][2], acck[4][2], accv[4][2];
        #pragma unroll
        for (int mt = 0; mt < 4; ++mt)
            #pragma unroll
            for (int nt = 0; nt < 2; ++nt) { accq[mt][nt] = fz; acck[mt][nt] = fz; accv[mt][nt] = fz; }

        const unsigned short* wq = wbf + ((h << 5) + l15) * 512 + (quad << 3);
        const unsigned short* wk = wq + 262144;
        const unsigned short* wv = wk + 262144;

        #pragma unroll 2
        for (int kk = 0; kk < 512; kk += 32) {
            short8 a[4], bq[2], bk2[2], bv2[2];
            #pragma unroll
            for (int mt = 0; mt < 4; ++mt)
                a[mt] = *(const short8*)&xs[((mt << 4) + l15) * 520 + kk + (quad << 3)];
            #pragma unroll
            for (int nt = 0; nt < 2; ++nt) {
                const int ro = (nt << 4) * 512 + kk;
                bq[nt]  = *(const short8*)(wq + ro);
                bk2[nt] = *(const short8*)(wk + ro);
                bv2[nt] = *(const short8*)(wv + ro);
            }
            #pragma unroll
            for (int nt = 0; nt < 2; ++nt)
                #pragma unroll
                for (int mt = 0; mt < 4; ++mt) {
                    accq[mt][nt] = __builtin_amdgcn_mfma_f32_16x16x32_bf16(a[mt], bq[nt],  accq[mt][nt], 0, 0, 0);
                    acck[mt][nt] = __builtin_amdgcn_mfma_f32_16x16x32_bf16(a[mt], bk2[nt], acck[mt][nt], 0, 0, 0);
                    accv[mt][nt] = __builtin_amdgcn_mfma_f32_16x16x32_bf16(a[mt], bv2[nt], accv[mt][nt], 0, 0, 0);
                }
        }

        #pragma unroll
        for (int nt = 0; nt < 2; ++nt) {
            const int cix = (h << 5) + (nt << 4) + l15;
            const float bq_ = qkv_b[cix];
            const float bk_ = qkv_b[512 + cix];
            const float bv_ = qkv_b[1024 + cix];
            #pragma unroll
            for (int mt = 0; mt < 4; ++mt) {
                short4v vv;
                #pragma unroll
                for (int r = 0; r < 4; ++r) {
                    const int row = (mt << 4) + (quad << 2) + r;
                    qbf[row * 40 + (nt << 4) + l15] = f2bf(accq[mt][nt][r] + bq_);
                    kbf[row * 40 + (nt << 4) + l15] = f2bf(acck[mt][nt][r] + bk_);
                    vv[r] = (short)f2bf(accv[mt][nt][r] + bv_);
                }
                *(short4v*)&vT[((nt << 4) + l15) * 72 + (mt << 4) + (quad << 2)] = vv;
            }
        }

        short8 qa[4], ka[4];
        #pragma unroll
        for (int t = 0; t < 4; ++t) {
            qa[t] = *(const short8*)&qbf[((t << 4) + l15) * 40 + (quad << 3)];
            ka[t] = *(const short8*)&kbf[((t << 4) + l15) * 40 + (quad << 3)];
        }
        floatx4 s4[4][4];
        #pragma unroll
        for (int mt = 0; mt < 4; ++mt)
            #pragma unroll
            for (int nt = 0; nt < 4; ++nt)
                s4[mt][nt] = __builtin_amdgcn_mfma_f32_16x16x32_bf16(qa[mt], ka[nt], fz, 0, 0, 0);

        int  gjv[4]; bool jrow[4], jcol[4];
        #pragma unroll
        for (int nt = 0; nt < 4; ++nt) {
            const int j  = (nt << 4) + l15;
            const int j2 = 63 - j;
            gjv[nt]  = 15 * (j2 >> 3) + (j2 & 7);
            jrow[nt] = (j >> 3) < 4;
            jcol[nt] = (j & 7) < 4;
        }
        #pragma unroll
        for (int mt = 0; mt < 4; ++mt) {
            const int i0  = (mt << 4) + (quad << 2);
            const int fi0 = 15 * (i0 >> 3) + (i0 & 7);
            const bool irow = (i0 >> 3) < 4;
            const bool icol = (i0 & 7) == 0;
            #pragma unroll
            for (int nt = 0; nt < 4; ++nt) {
                float mval = 0.0f;
                if ((mid & 2) && (irow != jrow[nt])) mval = -100.0f;
                if ((mid & 1) && (icol != jcol[nt])) mval = -100.0f;
                const float* bp = bias_table + (fi0 + gjv[nt]) * 16 + h;
                #pragma unroll
                for (int r = 0; r < 4; ++r)
                    s4[mt][nt][r] = s4[mt][nt][r] * scale + bp[r * 16] + mval;
            }
        }

        #pragma unroll
        for (int mt = 0; mt < 4; ++mt)
            #pragma unroll
            for (int r = 0; r < 4; ++r) {
                float m = fmaxf(fmaxf(s4[mt][0][r], s4[mt][1][r]),
                                fmaxf(s4[mt][2][r], s4[mt][3][r]));
                m = fmaxf(m, __shfl_xor(m, 1));
                m = fmaxf(m, __shfl_xor(m, 2));
                m = fmaxf(m, __shfl_xor(m, 4));
                m = fmaxf(m, __shfl_xor(m, 8));
                float loc = 0.0f;
                #pragma unroll
                for (int nt = 0; nt < 4; ++nt) {
                    s4[mt][nt][r] = __expf(s4[mt][nt][r] - m);
                    loc += s4[mt][nt][r];
                }
                loc += __shfl_xor(loc, 1);
                loc += __shfl_xor(loc, 2);
                loc += __shfl_xor(loc, 4);
                loc += __shfl_xor(loc, 8);
                const float inv = 1.0f / loc;
                const int row = (mt << 4) + (quad << 2) + r;
                #pragma unroll
                for (int nt = 0; nt < 4; ++nt)
                    pbf[row * 72 + (nt << 4) + l15] = f2bf(s4[mt][nt][r] * inv);
            }

        short8 pa[4][2], va[2][2];
        #pragma unroll
        for (int mt = 0; mt < 4; ++mt)
            #pragma unroll
            for (int ks = 0; ks < 2; ++ks)
                pa[mt][ks] = *(const short8*)&pbf[((mt << 4) + l15) * 72 + (ks << 5) + (quad << 3)];
        #pragma unroll
        for (int nt = 0; nt < 2; ++nt)
            #pragma unroll
            for (int ks = 0; ks < 2; ++ks)
                va[nt][ks] = *(const short8*)&vT[((nt << 4) + l15) * 72 + (ks << 5) + (quad << 3)];

        #pragma unroll
        for (int mt = 0; mt < 4; ++mt)
            #pragma unroll
            for (int nt = 0; nt < 2; ++nt) {
                floatx4 acc = fz;
                acc = __builtin_amdgcn_mfma_f32_16x16x32_bf16(pa[mt][0], va[nt][0], acc, 0, 0, 0);
                acc = __builtin_amdgcn_mfma_f32_16x16x32_bf16(pa[mt][1], va[nt][1], acc, 0, 0, 0);
                const int pi = ((mt << 1) + nt) << 1;
                po[hh][pi]     = (unsigned int)f2bf(acc[0]) | ((unsigned int)f2bf(acc[1]) << 16);
                po[hh][pi + 1] = (unsigned int)f2bf(acc[2]) | ((unsigned int)f2bf(acc[3]) << 16);
            }
    }
    __syncthreads();

    #pragma unroll
    for (int hh = 0; hh < 4; ++hh) {
        const int ch0 = (((wave << 2) + hh) << 5) + l15;
        #pragma unroll
        for (int mt = 0; mt < 4; ++mt)
            #pragma unroll
            for (int nt = 0; nt < 2; ++nt) {
                const int pi = ((mt << 1) + nt) << 1;
                #pragma unroll
                for (int r = 0; r < 4; ++r) {
                    const int row = (mt << 4) + (quad << 2) + r;
                    const unsigned int w = po[hh][pi + (r >> 1)];
                    xs[row * 520 + ch0 + (nt << 4)] =
                        (unsigned short)((w >> ((r & 1) << 4)) & 0xffffu);
                }
            }
    }
    __syncthreads();

    const unsigned short* pwb = wbf + 786432;
    for (int pass = 0; pass < 2; ++pass) {
        const int co0 = (wave << 7) + (pass << 6);
        floatx4 acc[4][4];
        #pragma unroll
        for (int mt = 0; mt < 4; ++mt)
            #pragma unroll
            for (int nt = 0; nt < 4; ++nt) acc[mt][nt] = fz;

        const unsigned short* wp = pwb + (co0 + l15) * 512 + (quad << 3);

        #pragma unroll 2
        for (int kk = 0; kk < 512; kk += 32) {
            short8 a[4], bfr[4];
            #pragma unroll
            for (int mt = 0; mt < 4; ++mt)
                a[mt] = *(const short8*)&xs[((mt << 4) + l15) * 520 + kk + (quad << 3)];
            #pragma unroll
            for (int nt = 0; nt < 4; ++nt)
                bfr[nt] = *(const short8*)(wp + (nt << 4) * 512 + kk);
            #pragma unroll
            for (int nt = 0; nt < 4; ++nt)
                #pragma unroll
                for (int mt = 0; mt < 4; ++mt)
                    acc[mt][nt] = __builtin_amdgcn_mfma_f32_16x16x32_bf16(a[mt], bfr[nt], acc[mt][nt], 0, 0, 0);
        }

        #pragma unroll
        for (int nt = 0; nt < 4; ++nt) {
            const float pb_ = proj_b[co0 + (nt << 4) + l15];
            #pragma unroll
            for (int mt = 0; mt < 4; ++mt)
                #pragma unroll
                for (int r = 0; r < 4; ++r) {
                    const int tok = (mt << 4) + (quad << 2) + r;
                    const int ty = tok >> 3, tx = tok & 7;
                    const int gh = ((wy << 3) + ty + 4) & 63;
                    const int gw = ((wx << 3) + tx + 4) & 63;
                    out[(((b << 12) + (gh << 6) + gw) << 9) + co0 + (nt << 4) + l15] =
                        acc[mt][nt][r] + pb_;
                }
        }
    }
}

// ---------------------------------------------------------------------------
extern "C" void kernel_launch(void* const* d_in, const int* in_sizes, int n_in,
                              void* d_out, int out_size, void* d_ws, size_t ws_size,
                              hipStream_t stream) {
    const float* query      = (const float*)d_in[0];
    const float* qkv_w      = (const float*)d_in[1];
    const float* qkv_b      = (const float*)d_in[2];
    const float* proj_w     = (const float*)d_in[3];
    const float* proj_b     = (const float*)d_in[4];
    const float* bias_table = (const float*)d_in[5];
    // d_in[6] = rel_index (closed-form, unused), d_in[7]=H, d_in[8]=W

    unsigned short* wbf = (unsigned short*)d_ws;              // 2 MiB weights
    unsigned short* xw  = wbf + 1048576;                      // 64 MiB tiled windows

    const size_t needB = (size_t)(1048576 + 33554432) * sizeof(unsigned short);

    if (ws_size >= needB) {
        hipLaunchKernelGGL(wcvt,     dim3(1024),  dim3(256), 0, stream, qkv_w, proj_w, wbf);
        hipLaunchKernelGGL(xcvt,     dim3(16384), dim3(256), 0, stream, query, xw);
        hipLaunchKernelGGL(k_fused3, dim3(1024),  dim3(256), 0, stream,
                           wbf, xw, qkv_b, proj_b, bias_table, (float*)d_out);
    } else {
        hipLaunchKernelGGL(wcvt,     dim3(1024), dim3(256), 0, stream, qkv_w, proj_w, wbf);
        hipLaunchKernelGGL(k_legacy, dim3(1024), dim3(256), 0, stream,
                           query, wbf, qkv_b, proj_b, bias_table, (float*)d_out);
    }
}

// Round 11
// 465.669 us; speedup vs baseline: 1.0367x; 1.0367x over previous
//
#include <hip/hip_runtime.h>

// ShiftWindowMSA (Swin) fused kernels for MI355X (gfx950).
// B=16, H=W=64, C=512, NH=16, hd=32, WS=8, SS=4 -> 1024 windows x 64 tokens.
//
// R11: monolith with LDS-STAGED QKV K-loop (m97 recipe, reg-staged variant):
// per head-quad hq, the block stages A[64x32] (window) + B[384x32] (q/k/v
// weights for heads hq*4..hq*4+3) per K-step into swizzled LDS; inner loop
// reads LDS (~12cy) not L2 (~200-900cy). Window read 4x/block (was 16x).
// Stage buffer (28672 B) time-multiplexes with attention scratch -> LDS 49152.
// Head ownership h = hq*4+wave; proj half-K exchange remapped (ch=rnd*256+c').
// Evidence ledger: K-loop-from-L2 is latency-pinned at ~350 TF at ANY
// occupancy (R1/R9 412us; R10 3blk/CU -> 298MB FETCH L2-thrash, 477us);
// (256,3) always spills (R2/R8); splits pay HBM round-trips (R5/R7).
// Prefetch placed after 1st barrier so its vmcnt-drain overlaps MFMA.
// Fallback (ws < 66 MiB): R0 monolithic k_legacy.

typedef short  short8  __attribute__((ext_vector_type(8)));
typedef short  short4v __attribute__((ext_vector_type(4)));
typedef float  floatx4 __attribute__((ext_vector_type(4)));

#define DEVI static __device__ __forceinline__

DEVI unsigned short f2bf(float f) {
    union { float f; unsigned int u; } v;
    v.f = f;
    return (unsigned short)((v.u + 0x7fffu + ((v.u >> 16) & 1u)) >> 16);
}

// ---------------------------------------------------------------------------
// wcvt: qkv_w (1536x512) then proj_w (512x512) fp32 -> bf16 into wbf.
// ---------------------------------------------------------------------------
__global__ void wcvt(const float* __restrict__ qkv_w,
                     const float* __restrict__ proj_w,
                     unsigned short* __restrict__ wbf) {
    const int idx = ((blockIdx.x << 8) + threadIdx.x) << 2;
    const float* src = (idx < 786432) ? (qkv_w + idx) : (proj_w + (idx - 786432));
    const floatx4 v = *(const floatx4*)src;
    short4v o;
    o[0] = (short)f2bf(v[0]); o[1] = (short)f2bf(v[1]);
    o[2] = (short)f2bf(v[2]); o[3] = (short)f2bf(v[3]);
    *(short4v*)(wbf + idx) = o;
}

// ---------------------------------------------------------------------------
// xcvt: gather cyclic-shifted windows of query -> xw bf16 [win][kc][tok][32].
// ---------------------------------------------------------------------------
__global__ void xcvt(const float* __restrict__ query,
                     unsigned short* __restrict__ xw) {
    const int bid = blockIdx.x;
    const int x   = bid & 7;
    const int s   = bid >> 3;                           // 0..2047
    const int win = (x << 7) + (s >> 4);
    const int rem = ((s & 15) << 8) + threadIdx.x;      // 0..4095
    const int jc  = rem & 3;                            // 8-short chunk in 32
    const int tok = (rem >> 2) & 63;
    const int kc  = rem >> 8;                           // 0..15
    const int b   = win >> 6, wy = (win >> 3) & 7, wx = win & 7;
    const int ty  = tok >> 3, tx = tok & 7;
    const int gh  = ((wy << 3) + ty + 4) & 63;
    const int gw  = ((wx << 3) + tx + 4) & 63;
    const float* src = query + (((b << 12) + (gh << 6) + gw) << 9) + (kc << 5) + (jc << 3);
    const floatx4 v0 = *(const floatx4*)src;
    const floatx4 v1 = *(const floatx4*)(src + 4);
    short8 sv;
    sv[0] = (short)f2bf(v0[0]); sv[1] = (short)f2bf(v0[1]);
    sv[2] = (short)f2bf(v0[2]); sv[3] = (short)f2bf(v0[3]);
    sv[4] = (short)f2bf(v1[0]); sv[5] = (short)f2bf(v1[1]);
    sv[6] = (short)f2bf(v1[2]); sv[7] = (short)f2bf(v1[3]);
    *(short8*)(xw + (win << 15) + (kc << 11) + (tok << 5) + (jc << 3)) = sv;
}

// ---------------------------------------------------------------------------
// k_fused4: 1 block = 1 window, 4 waves; per head-quad hq, wave owns head
// h = hq*4+wave. QKV GEMM with LDS-staged A/B tiles; attention from proven
// swizzled scratch; proj via half-K exchange (ch = rnd*256 + c').
// LDS 49152 B: stage stA[64][32]+stB[384][32] (28672 B) overlays the 4x6144-sh
// attention scratch and the 64x264 proj exchange (time-multiplexed).
// ---------------------------------------------------------------------------
__global__ __launch_bounds__(256, 2)
void k_fused4(const unsigned short* __restrict__ wbf,
              const unsigned short* __restrict__ xw,
              const float* __restrict__ qkv_b,
              const float* __restrict__ proj_b,
              const float* __restrict__ bias_table,
              float* __restrict__ out)
{
    __shared__ __align__(16) unsigned short smem[24576];   // 49152 B

    const int tid  = threadIdx.x;
    const int lane = tid & 63;
    const int l15  = lane & 15;
    const int quad = lane >> 4;
    const int wave = tid >> 6;

    const int win = blockIdx.x;
    const int b   = win >> 6;
    const int wy  = (win >> 3) & 7;
    const int wx  = win & 7;
    const int mid = ((wy == 7) ? 2 : 0) | ((wx == 7) ? 1 : 0);

    unsigned short* stA = smem;                         // [64][32] swizzled (2048 sh)
    unsigned short* stB = smem + 2048;                  // [384][32] swizzled (12288 sh)
    unsigned short* wbs = smem + wave * 6144;           // attention scratch (overlays stage)
    unsigned short* qbf = wbs;                          // [64][32] swizzled
    unsigned short* kbf = wbs + 2048;                   // [64][32] swizzled
    unsigned short* vT  = wbs + 4096;                   // [32][64] swizzled
    unsigned short* pbf = wbs;                          // [64][64] swizzled, overlays q+k

    const int sw4 = (l15 & 3) ^ (l15 >> 2);             // frag-read swizzle (A,B,q,k)
    const int sw8 = (l15 & 7) ^ (l15 >> 3);             // vT/p read swizzle

    const float scale = 0.17677669529663687f;           // 1/sqrt(32)
    const floatx4 fz = {0.f, 0.f, 0.f, 0.f};

    unsigned int po[4][16];                             // po[hq] = y of head hq*4+wave

    // ---- per-thread staging decode (constant across steps/hq) ----
    const int s_tok = tid >> 2;                                          // A row (token)
    const int a_ko  = (((tid & 3) ^ (s_tok & 3) ^ ((s_tok >> 2) & 3)) << 3);
    const unsigned short* a_src = xw + (win << 15) + s_tok * 32 + a_ko;  // + kc*2048
    const int sB    = ((tid >> 2) & 3) ^ ((tid >> 4) & 3);               // B col swizzle
    const int b_ko  = (((tid & 3) ^ sB) << 3);

    for (int hq = 0; hq < 4; ++hq) {
        const int h = (hq << 2) + wave;

        // per-issue B source row bases for this hq
        int rowb[6];
        #pragma unroll
        for (int i = 0; i < 6; ++i) {
            const int cpp = (i << 6) + (tid >> 2);      // c'' = mat*128 + w*32 + c
            const int mat = cpp >> 7;
            const int wv_ = (cpp >> 5) & 3;
            const int c   = cpp & 31;
            rowb[i] = mat * 262144 + (((hq << 2) + wv_) * 32 + c) * 512 + b_ko;
        }

        floatx4 accq[4][2], acck[4][2], accv[4][2];
        #pragma unroll
        for (int mt = 0; mt < 4; ++mt)
            #pragma unroll
            for (int nt = 0; nt < 2; ++nt) { accq[mt][nt] = fz; acck[mt][nt] = fz; accv[mt][nt] = fz; }

        // prologue: prefetch kk=0 into regs
        short8 pga, pgb[6];
        pga = *(const short8*)a_src;
        #pragma unroll
        for (int i = 0; i < 6; ++i)
            pgb[i] = *(const short8*)(wbf + rowb[i]);

        for (int ks = 0; ks < 16; ++ks) {
            const int kn = ((ks + 1) & 15) << 5;        // next kk (wraps, harmless)
            // write staged regs -> LDS (linear dest, pre-swizzled source)
            *(short8*)(stA + (tid << 3)) = pga;
            #pragma unroll
            for (int i = 0; i < 6; ++i)
                *(short8*)(stB + (i << 11) + (tid << 3)) = pgb[i];
            __syncthreads();                            // stage visible to all waves
            // prefetch next step (drained at 2nd barrier; overlaps reads+MFMA)
            pga = *(const short8*)(a_src + ((kn >> 5) << 11));
            #pragma unroll
            for (int i = 0; i < 6; ++i)
                pgb[i] = *(const short8*)(wbf + rowb[i] + kn);
            // fragment reads (2-way bank, free)
            short8 af[4], bqf[2], bkf[2], bvf[2];
            const int coff = (quad ^ sw4) << 3;
            #pragma unroll
            for (int mt = 0; mt < 4; ++mt)
                af[mt] = *(const short8*)(stA + (((mt << 4) + l15) << 5) + coff);
            #pragma unroll
            for (int nt = 0; nt < 2; ++nt) {
                const int cq_ = (wave << 5) + (nt << 4) + l15;
                bqf[nt] = *(const short8*)(stB + (cq_ << 5) + coff);
                bkf[nt] = *(const short8*)(stB + ((128 + cq_) << 5) + coff);
                bvf[nt] = *(const short8*)(stB + ((256 + cq_) << 5) + coff);
            }
            #pragma unroll
            for (int nt = 0; nt < 2; ++nt)
                #pragma unroll
                for (int mt = 0; mt < 4; ++mt) {
                    accq[mt][nt] = __builtin_amdgcn_mfma_f32_16x16x32_bf16(af[mt], bqf[nt], accq[mt][nt], 0, 0, 0);
                    acck[mt][nt] = __builtin_amdgcn_mfma_f32_16x16x32_bf16(af[mt], bkf[nt], acck[mt][nt], 0, 0, 0);
                    accv[mt][nt] = __builtin_amdgcn_mfma_f32_16x16x32_bf16(af[mt], bvf[nt], accv[mt][nt], 0, 0, 0);
                }
            __syncthreads();                            // all reads done before overwrite
        }

        // ---- bias + stage q,k (swizzled) and vT (swizzled) into scratch -----
        #pragma unroll
        for (int nt = 0; nt < 2; ++nt) {
            const int cix = (h << 5) + (nt << 4) + l15;
            const float bq_ = qkv_b[cix];
            const float bk_ = qkv_b[512 + cix];
            const float bv_ = qkv_b[1024 + cix];
            #pragma unroll
            for (int mt = 0; mt < 4; ++mt) {
                short4v vv;
                #pragma unroll
                for (int r = 0; r < 4; ++r) {
                    const int row = (mt << 4) + (quad << 2) + r;
                    const int ph  = (2 * nt + (l15 >> 3)) ^ (row & 3) ^ ((row >> 2) & 3);
                    const int off = (row << 5) + (l15 & 7) + (ph << 3);
                    qbf[off] = f2bf(accq[mt][nt][r] + bq_);
                    kbf[off] = f2bf(acck[mt][nt][r] + bk_);
                    vv[r] = (short)f2bf(accv[mt][nt][r] + bv_);
                }
                const int vph = (2 * mt + (quad >> 1)) ^ sw8;
                *(short4v*)&vT[(((nt << 4) + l15) << 6) + ((quad & 1) << 2) + (vph << 3)] = vv;
            }
        }
        // (no barrier: scratch is wave-private)

        // ---------------- Q K^T ----------------------------------------------
        short8 qa[4], ka[4];
        #pragma unroll
        for (int t = 0; t < 4; ++t) {
            const int off = ((((t << 4) + l15)) << 5) + ((quad ^ sw4) << 3);
            qa[t] = *(const short8*)&qbf[off];
            ka[t] = *(const short8*)&kbf[off];
        }
        floatx4 s4[4][4];
        #pragma unroll
        for (int mt = 0; mt < 4; ++mt)
            #pragma unroll
            for (int nt = 0; nt < 4; ++nt)
                s4[mt][nt] = __builtin_amdgcn_mfma_f32_16x16x32_bf16(qa[mt], ka[nt], fz, 0, 0, 0);

        // ------- logits: scale + rel-pos bias (closed-form idx) + shift mask --
        int  gjv[4]; bool jrow[4], jcol[4];
        #pragma unroll
        for (int nt = 0; nt < 4; ++nt) {
            const int j  = (nt << 4) + l15;
            const int j2 = 63 - j;
            gjv[nt]  = 15 * (j2 >> 3) + (j2 & 7);
            jrow[nt] = (j >> 3) < 4;
            jcol[nt] = (j & 7) < 4;
        }
        #pragma unroll
        for (int mt = 0; mt < 4; ++mt) {
            const int i0  = (mt << 4) + (quad << 2);
            const int fi0 = 15 * (i0 >> 3) + (i0 & 7);
            const bool irow = (i0 >> 3) < 4;
            const bool icol = (i0 & 7) == 0;
            #pragma unroll
            for (int nt = 0; nt < 4; ++nt) {
                float mval = 0.0f;
                if ((mid & 2) && (irow != jrow[nt])) mval = -100.0f;
                if ((mid & 1) && (icol != jcol[nt])) mval = -100.0f;
                const float* bp = bias_table + (fi0 + gjv[nt]) * 16 + h;
                #pragma unroll
                for (int r = 0; r < 4; ++r)
                    s4[mt][nt][r] = s4[mt][nt][r] * scale + bp[r * 16] + mval;
            }
        }

        // ---- softmax (max-subtracted, normalized) -> P in swizzled LDS -------
        #pragma unroll
        for (int mt = 0; mt < 4; ++mt)
            #pragma unroll
            for (int r = 0; r < 4; ++r) {
                float m = fmaxf(fmaxf(s4[mt][0][r], s4[mt][1][r]),
                                fmaxf(s4[mt][2][r], s4[mt][3][r]));
                m = fmaxf(m, __shfl_xor(m, 1));
                m = fmaxf(m, __shfl_xor(m, 2));
                m = fmaxf(m, __shfl_xor(m, 4));
                m = fmaxf(m, __shfl_xor(m, 8));
                float loc = 0.0f;
                #pragma unroll
                for (int nt = 0; nt < 4; ++nt) {
                    s4[mt][nt][r] = __expf(s4[mt][nt][r] - m);
                    loc += s4[mt][nt][r];
                }
                loc += __shfl_xor(loc, 1);
                loc += __shfl_xor(loc, 2);
                loc += __shfl_xor(loc, 4);
                loc += __shfl_xor(loc, 8);
                const float inv = 1.0f / loc;           // loc >= 1 (max entry = 1)
                const int row = (mt << 4) + (quad << 2) + r;
                #pragma unroll
                for (int nt = 0; nt < 4; ++nt) {
                    const int ph = (2 * nt + (l15 >> 3)) ^ (row & 7) ^ ((row >> 3) & 1);
                    pbf[(row << 6) + (l15 & 7) + (ph << 3)] = f2bf(s4[mt][nt][r] * inv);
                }
            }
        // (no barrier: pbf is wave-private)

        // ---------------- P V -> po[hq] (packed bf16) -------------------------
        short8 pa[4][2], va[2][2];
        #pragma unroll
        for (int mt = 0; mt < 4; ++mt)
            #pragma unroll
            for (int ks = 0; ks < 2; ++ks)
                pa[mt][ks] = *(const short8*)&pbf[((((mt << 4) + l15)) << 6) + ((((ks << 2) + quad) ^ sw8) << 3)];
        #pragma unroll
        for (int nt = 0; nt < 2; ++nt)
            #pragma unroll
            for (int ks = 0; ks < 2; ++ks)
                va[nt][ks] = *(const short8*)&vT[((((nt << 4) + l15)) << 6) + ((((ks << 2) + quad) ^ sw8) << 3)];

        #pragma unroll
        for (int mt = 0; mt < 4; ++mt)
            #pragma unroll
            for (int nt = 0; nt < 2; ++nt) {
                floatx4 acc = fz;
                acc = __builtin_amdgcn_mfma_f32_16x16x32_bf16(pa[mt][0], va[nt][0], acc, 0, 0, 0);
                acc = __builtin_amdgcn_mfma_f32_16x16x32_bf16(pa[mt][1], va[nt][1], acc, 0, 0, 0);
                const int pi = ((mt << 1) + nt) << 1;
                po[hq][pi]     = (unsigned int)f2bf(acc[0]) | ((unsigned int)f2bf(acc[1]) << 16);
                po[hq][pi + 1] = (unsigned int)f2bf(acc[2]) | ((unsigned int)f2bf(acc[3]) << 16);
            }

        __syncthreads();   // scratch reads done before next hq's staging clobbers
    }

    // ---------------- proj with half-K exchange -------------------------------
    // xsh[64][264] bf16 (16896 sh) overlays everything (dead now).
    // Round rnd publishes heads 8rnd..8rnd+7 (hq in {2rnd,2rnd+1}):
    // real ch = rnd*256 + c', c' = g*128 + wave*32 + off.
    unsigned short* xsh = smem;
    const unsigned short* pwb = wbf + 786432;

    for (int pass = 0; pass < 2; ++pass) {
        const int co0 = (wave << 7) + (pass << 6);
        floatx4 acc[4][4];
        #pragma unroll
        for (int mt = 0; mt < 4; ++mt)
            #pragma unroll
            for (int nt = 0; nt < 4; ++nt) acc[mt][nt] = fz;

        const unsigned short* wp = pwb + (co0 + l15) * 512;

        for (int rnd = 0; rnd < 2; ++rnd) {
            __syncthreads();   // previous readers of xsh done
            #pragma unroll
            for (int g = 0; g < 2; ++g) {
                const int hq = (rnd << 1) + g;
                const int c0 = (g << 7) + (wave << 5) + l15;
                #pragma unroll
                for (int mt = 0; mt < 4; ++mt)
                    #pragma unroll
                    for (int nt = 0; nt < 2; ++nt) {
                        const int pi = ((mt << 1) + nt) << 1;
                        #pragma unroll
                        for (int r = 0; r < 4; ++r) {
                            const int row = (mt << 4) + (quad << 2) + r;
                            const unsigned int w = po[hq][pi + (r >> 1)];
                            xsh[row * 264 + c0 + (nt << 4)] =
                                (unsigned short)((w >> ((r & 1) << 4)) & 0xffffu);
                        }
                    }
            }
            __syncthreads();   // all waves' half published

            #pragma unroll 2
            for (int kk = 0; kk < 256; kk += 32) {
                const int rb = (rnd << 8) + kk + (quad << 3);
                short8 a[4], bfr[4];
                #pragma unroll
                for (int mt = 0; mt < 4; ++mt)
                    a[mt] = *(const short8*)&xsh[((mt << 4) + l15) * 264 + kk + (quad << 3)];
                #pragma unroll
                for (int nt = 0; nt < 4; ++nt)
                    bfr[nt] = *(const short8*)(wp + (nt << 4) * 512 + rb);
                #pragma unroll
                for (int nt = 0; nt < 4; ++nt)
                    #pragma unroll
                    for (int mt = 0; mt < 4; ++mt)
                        acc[mt][nt] = __builtin_amdgcn_mfma_f32_16x16x32_bf16(a[mt], bfr[nt], acc[mt][nt], 0, 0, 0);
            }
        }

        // epilogue: bias + window-reverse + reverse-roll scatter
        #pragma unroll
        for (int nt = 0; nt < 4; ++nt) {
            const float pb_ = proj_b[co0 + (nt << 4) + l15];
            #pragma unroll
            for (int mt = 0; mt < 4; ++mt)
                #pragma unroll
                for (int r = 0; r < 4; ++r) {
                    const int tok = (mt << 4) + (quad << 2) + r;
                    const int ty = tok >> 3, tx = tok & 7;
                    const int gh = ((wy << 3) + ty + 4) & 63;
                    const int gw = ((wx << 3) + tx + 4) & 63;
                    out[(((b << 12) + (gh << 6) + gw) << 9) + co0 + (nt << 4) + l15] =
                        acc[mt][nt][r] + pb_;
                }
        }
    }
}

// ---------------------------------------------------------------------------
// Fallback (ws < 66 MiB): R0 monolithic kernel (stages window in LDS).
// ---------------------------------------------------------------------------
__global__ __launch_bounds__(256, 1)
void k_legacy(const float* __restrict__ query,
              const unsigned short* __restrict__ wbf,
              const float* __restrict__ qkv_b,
              const float* __restrict__ proj_b,
              const float* __restrict__ bias_table,
              float* __restrict__ out)
{
    __shared__ __align__(16) unsigned short smem[62976];

    const int tid  = threadIdx.x;
    const int lane = tid & 63;
    const int l15  = lane & 15;
    const int quad = lane >> 4;
    const int wave = tid >> 6;

    const int win = blockIdx.x;
    const int b   = win >> 6;
    const int wy  = (win >> 3) & 7;
    const int wx  = win & 7;
    const int mid = ((wy == 7) ? 2 : 0) | ((wx == 7) ? 1 : 0);

    unsigned short* xs  = smem;
    unsigned short* wb  = smem + 33280 + wave * 7424;
    unsigned short* qbf = wb;
    unsigned short* kbf = wb + 2560;
    unsigned short* vT  = wb + 5120;
    unsigned short* pbf = wb;

    #pragma unroll
    for (int it = 0; it < 32; ++it) {
        const int c   = tid + (it << 8);
        const int tok = c >> 7;
        const int fo  = (c & 127) << 2;
        const int ty  = tok >> 3, tx = tok & 7;
        const int gh  = ((wy << 3) + ty + 4) & 63;
        const int gw  = ((wx << 3) + tx + 4) & 63;
        const floatx4 v = *(const floatx4*)(query + (((b << 12) + (gh << 6) + gw) << 9) + fo);
        short4v s;
        s[0] = (short)f2bf(v[0]); s[1] = (short)f2bf(v[1]);
        s[2] = (short)f2bf(v[2]); s[3] = (short)f2bf(v[3]);
        *(short4v*)&xs[tok * 520 + fo] = s;
    }
    __syncthreads();

    const float scale = 0.17677669529663687f;
    const floatx4 fz = {0.f, 0.f, 0.f, 0.f};
    unsigned int po[4][16];

    for (int hh = 0; hh < 4; ++hh) {
        const int h = (wave << 2) + hh;
        floatx4 accq[4][2], acck[4][2], accv[4][2];
        #pragma unroll
        for (int mt = 0; mt < 4; ++mt)
            #pragma unroll
            for (int nt = 0; nt < 2; ++nt) { accq[mt][nt] = fz; acck[mt][nt] = fz; accv[mt][nt] = fz; }

        const unsigned short* wq = wbf + ((h << 5) + l15) * 512 + (quad << 3);
        const unsigned short* wk = wq + 262144;
        const unsigned short* wv = wk + 262144;

        #pragma unroll 2
        for (int kk = 0; kk < 512; kk += 32) {
            short8 a[4], bq[2], bk2[2], bv2[2];
            #pragma unroll
            for (int mt = 0; mt < 4; ++mt)
                a[mt] = *(const short8*)&xs[((mt << 4) + l15) * 520 + kk + (quad << 3)];
            #pragma unroll
            for (int nt = 0; nt < 2; ++nt) {
                const int ro = (nt << 4) * 512 + kk;
                bq[nt]  = *(const short8*)(wq + ro);
                bk2[nt] = *(const short8*)(wk + ro);
                bv2[nt] = *(const short8*)(wv + ro);
            }
            #pragma unroll
            for (int nt = 0; nt < 2; ++nt)
                #pragma unroll
                for (int mt = 0; mt < 4; ++mt) {
                    accq[mt][nt] = __builtin_amdgcn_mfma_f32_16x16x32_bf16(a[mt], bq[nt],  accq[mt][nt], 0, 0, 0);
                    acck[mt][nt] = __builtin_amdgcn_mfma_f32_16x16x32_bf16(a[mt], bk2[nt], acck[mt][nt], 0, 0, 0);
                    accv[mt][nt] = __builtin_amdgcn_mfma_f32_16x16x32_bf16(a[mt], bv2[nt], accv[mt][nt], 0, 0, 0);
                }
        }

        #pragma unroll
        for (int nt = 0; nt < 2; ++nt) {
            const int cix = (h << 5) + (nt << 4) + l15;
            const float bq_ = qkv_b[cix];
            const float bk_ = qkv_b[512 + cix];
            const float bv_ = qkv_b[1024 + cix];
            #pragma unroll
            for (int mt = 0; mt < 4; ++mt) {
                short4v vv;
                #pragma unroll
                for (int r = 0; r < 4; ++r) {
                    const int row = (mt << 4) + (quad << 2) + r;
                    qbf[row * 40 + (nt << 4) + l15] = f2bf(accq[mt][nt][r] + bq_);
                    kbf[row * 40 + (nt << 4) + l15] = f2bf(acck[mt][nt][r] + bk_);
                    vv[r] = (short)f2bf(accv[mt][nt][r] + bv_);
                }
                *(short4v*)&vT[((nt << 4) + l15) * 72 + (mt << 4) + (quad << 2)] = vv;
            }
        }

        short8 qa[4], ka[4];
        #pragma unroll
        for (int t = 0; t < 4; ++t) {
            qa[t] = *(const short8*)&qbf[((t << 4) + l15) * 40 + (quad << 3)];
            ka[t] = *(const short8*)&kbf[((t << 4) + l15) * 40 + (quad << 3)];
        }
        floatx4 s4[4][4];
        #pragma unroll
        for (int mt = 0; mt < 4; ++mt)
            #pragma unroll
            for (int nt = 0; nt < 4; ++nt)
                s4[mt][nt] = __builtin_amdgcn_mfma_f32_16x16x32_bf16(qa[mt], ka[nt], fz, 0, 0, 0);

        int  gjv[4]; bool jrow[4], jcol[4];
        #pragma unroll
        for (int nt = 0; nt < 4; ++nt) {
            const int j  = (nt << 4) + l15;
            const int j2 = 63 - j;
            gjv[nt]  = 15 * (j2 >> 3) + (j2 & 7);
            jrow[nt] = (j >> 3) < 4;
            jcol[nt] = (j & 7) < 4;
        }
        #pragma unroll
        for (int mt = 0; mt < 4; ++mt) {
            const int i0  = (mt << 4) + (quad << 2);
            const int fi0 = 15 * (i0 >> 3) + (i0 & 7);
            const bool irow = (i0 >> 3) < 4;
            const bool icol = (i0 & 7) == 0;
            #pragma unroll
            for (int nt = 0; nt < 4; ++nt) {
                float mval = 0.0f;
                if ((mid & 2) && (irow != jrow[nt])) mval = -100.0f;
                if ((mid & 1) && (icol != jcol[nt])) mval = -100.0f;
                const float* bp = bias_table + (fi0 + gjv[nt]) * 16 + h;
                #pragma unroll
                for (int r = 0; r < 4; ++r)
                    s4[mt][nt][r] = s4[mt][nt][r] * scale + bp[r * 16] + mval;
            }
        }

        #pragma unroll
        for (int mt = 0; mt < 4; ++mt)
            #pragma unroll
            for (int r = 0; r < 4; ++r) {
                float m = fmaxf(fmaxf(s4[mt][0][r], s4[mt][1][r]),
                                fmaxf(s4[mt][2][r], s4[mt][3][r]));
                m = fmaxf(m, __shfl_xor(m, 1));
                m = fmaxf(m, __shfl_xor(m, 2));
                m = fmaxf(m, __shfl_xor(m, 4));
                m = fmaxf(m, __shfl_xor(m, 8));
                float loc = 0.0f;
                #pragma unroll
                for (int nt = 0; nt < 4; ++nt) {
                    s4[mt][nt][r] = __expf(s4[mt][nt][r] - m);
                    loc += s4[mt][nt][r];
                }
                loc += __shfl_xor(loc, 1);
                loc += __shfl_xor(loc, 2);
                loc += __shfl_xor(loc, 4);
                loc += __shfl_xor(loc, 8);
                const float inv = 1.0f / loc;
                const int row = (mt << 4) + (quad << 2) + r;
                #pragma unroll
                for (int nt = 0; nt < 4; ++nt)
                    pbf[row * 72 + (nt << 4) + l15] = f2bf(s4[mt][nt][r] * inv);
            }

        short8 pa[4][2], va[2][2];
        #pragma unroll
        for (int mt = 0; mt < 4; ++mt)
            #pragma unroll
            for (int ks = 0; ks < 2; ++ks)
                pa[mt][ks] = *(const short8*)&pbf[((mt << 4) + l15) * 72 + (ks << 5) + (quad << 3)];
        #pragma unroll
        for (int nt = 0; nt < 2; ++nt)
            #pragma unroll
            for (int ks = 0; ks < 2; ++ks)
                va[nt][ks] = *(const short8*)&vT[((nt << 4) + l15) * 72 + (ks << 5) + (quad << 3)];

        #pragma unroll
        for (int mt = 0; mt < 4; ++mt)
            #pragma unroll
            for (int nt = 0; nt < 2; ++nt) {
                floatx4 acc = fz;
                acc = __builtin_amdgcn_mfma_f32_16x16x32_bf16(pa[mt][0], va[nt][0], acc, 0, 0, 0);
                acc = __builtin_amdgcn_mfma_f32_16x16x32_bf16(pa[mt][1], va[nt][1], acc, 0, 0, 0);
                const int pi = ((mt << 1) + nt) << 1;
                po[hh][pi]     = (unsigned int)f2bf(acc[0]) | ((unsigned int)f2bf(acc[1]) << 16);
                po[hh][pi + 1] = (unsigned int)f2bf(acc[2]) | ((unsigned int)f2bf(acc[3]) << 16);
            }
    }
    __syncthreads();

    #pragma unroll
    for (int hh = 0; hh < 4; ++hh) {
        const int ch0 = (((wave << 2) + hh) << 5) + l15;
        #pragma unroll
        for (int mt = 0; mt < 4; ++mt)
            #pragma unroll
            for (int nt = 0; nt < 2; ++nt) {
                const int pi = ((mt << 1) + nt) << 1;
                #pragma unroll
                for (int r = 0; r < 4; ++r) {
                    const int row = (mt << 4) + (quad << 2) + r;
                    const unsigned int w = po[hh][pi + (r >> 1)];
                    xs[row * 520 + ch0 + (nt << 4)] =
                        (unsigned short)((w >> ((r & 1) << 4)) & 0xffffu);
                }
            }
    }
    __syncthreads();

    const unsigned short* pwb = wbf + 786432;
    for (int pass = 0; pass < 2; ++pass) {
        const int co0 = (wave << 7) + (pass << 6);
        floatx4 acc[4][4];
        #pragma unroll
        for (int mt = 0; mt < 4; ++mt)
            #pragma unroll
            for (int nt = 0; nt < 4; ++nt) acc[mt][nt] = fz;

        const unsigned short* wp = pwb + (co0 + l15) * 512 + (quad << 3);

        #pragma unroll 2
        for (int kk = 0; kk < 512; kk += 32) {
            short8 a[4], bfr[4];
            #pragma unroll
            for (int mt = 0; mt < 4; ++mt)
                a[mt] = *(const short8*)&xs[((mt << 4) + l15) * 520 + kk + (quad << 3)];
            #pragma unroll
            for (int nt = 0; nt < 4; ++nt)
                bfr[nt] = *(const short8*)(wp + (nt << 4) * 512 + kk);
            #pragma unroll
            for (int nt = 0; nt < 4; ++nt)
                #pragma unroll
                for (int mt = 0; mt < 4; ++mt)
                    acc[mt][nt] = __builtin_amdgcn_mfma_f32_16x16x32_bf16(a[mt], bfr[nt], acc[mt][nt], 0, 0, 0);
        }

        #pragma unroll
        for (int nt = 0; nt < 4; ++nt) {
            const float pb_ = proj_b[co0 + (nt << 4) + l15];
            #pragma unroll
            for (int mt = 0; mt < 4; ++mt)
                #pragma unroll
                for (int r = 0; r < 4; ++r) {
                    const int tok = (mt << 4) + (quad << 2) + r;
                    const int ty = tok >> 3, tx = tok & 7;
                    const int gh = ((wy << 3) + ty + 4) & 63;
                    const int gw = ((wx << 3) + tx + 4) & 63;
                    out[(((b << 12) + (gh << 6) + gw) << 9) + co0 + (nt << 4) + l15] =
                        acc[mt][nt][r] + pb_;
                }
        }
    }
}

// ---------------------------------------------------------------------------
extern "C" void kernel_launch(void* const* d_in, const int* in_sizes, int n_in,
                              void* d_out, int out_size, void* d_ws, size_t ws_size,
                              hipStream_t stream) {
    const float* query      = (const float*)d_in[0];
    const float* qkv_w      = (const float*)d_in[1];
    const float* qkv_b      = (const float*)d_in[2];
    const float* proj_w     = (const float*)d_in[3];
    const float* proj_b     = (const float*)d_in[4];
    const float* bias_table = (const float*)d_in[5];
    // d_in[6] = rel_index (closed-form, unused), d_in[7]=H, d_in[8]=W

    unsigned short* wbf = (unsigned short*)d_ws;              // 2 MiB weights
    unsigned short* xw  = wbf + 1048576;                      // 64 MiB tiled windows

    const size_t needB = (size_t)(1048576 + 33554432) * sizeof(unsigned short);

    if (ws_size >= needB) {
        hipLaunchKernelGGL(wcvt,     dim3(1024),  dim3(256), 0, stream, qkv_w, proj_w, wbf);
        hipLaunchKernelGGL(xcvt,     dim3(16384), dim3(256), 0, stream, query, xw);
        hipLaunchKernelGGL(k_fused4, dim3(1024),  dim3(256), 0, stream,
                           wbf, xw, qkv_b, proj_b, bias_table, (float*)d_out);
    } else {
        hipLaunchKernelGGL(wcvt,     dim3(1024), dim3(256), 0, stream, qkv_w, proj_w, wbf);
        hipLaunchKernelGGL(k_legacy, dim3(1024), dim3(256), 0, stream,
                           query, wbf, qkv_b, proj_b, bias_table, (float*)d_out);
    }
}